// Round 19
// baseline (113.796 us; speedup 1.0000x reference)
//
#include <hip/hip_runtime.h>
#include <hip/hip_bf16.h>

#define NB 32768      // batch rows per node
#define CD 128        // input channels (K of every GEMM term)
#define OUTW 1536     // 6*256 output cols

// d_ws weight matrices, each [256 out][128 k] bf16 (32768 shorts):
#define PW_P  0        // Wl            (U = T·Wl)
#define PW_M0 32768    // Wr - Wl/5     (nodes 0,1)
#define PW_M2 65536    // Wr - Wl/4     (nodes 2..5 own term)
#define PW_N  98304    // -Wl/4         (partner term)

typedef __attribute__((ext_vector_type(8))) short short8;
typedef __attribute__((ext_vector_type(4))) float f32x4;

// hardware f32->bf16 (RNE)
static __device__ __forceinline__ short f2bf(float f) {
    union { __bf16 b; short s; } u;
    u.b = (__bf16)f;
    return u.s;
}

static __device__ __forceinline__ short8 pack8(f32x4 a, f32x4 b) {
    short8 p;
    #pragma unroll
    for (int j = 0; j < 4; ++j) { p[j] = f2bf(a[j]); p[4 + j] = f2bf(b[j]); }
    return p;
}

// ---- prologue: 4 combined weight matrices (aggregation pushed past the
// GEMM; R18-validated: absmax 0.03125)
__global__ void prep_w(const float* __restrict__ Wl, const float* __restrict__ Wr,
                       short* __restrict__ Wb) {
    const int i = (blockIdx.x * 256 + threadIdx.x) * 8;   // o*128 + k
    const int o = i >> 7;
    const int k = i & 127;
    f32x4 l0 = *(const f32x4*)(Wl + o * CD + k);
    f32x4 l1 = *(const f32x4*)(Wl + o * CD + k + 4);
    f32x4 r0 = *(const f32x4*)(Wr + o * CD + k);
    f32x4 r1 = *(const f32x4*)(Wr + o * CD + k + 4);
    *(short8*)(Wb + PW_P  + i) = pack8(l0, l1);
    *(short8*)(Wb + PW_M0 + i) = pack8(r0 - 0.2f  * l0, r1 - 0.2f  * l1);
    *(short8*)(Wb + PW_M2 + i) = pack8(r0 - 0.25f * l0, r1 - 0.25f * l1);
    *(short8*)(Wb + PW_N  + i) = pack8(-0.25f * l0, -0.25f * l1);
}

// R19: barrier-free, LDS-free, wave-independent streaming.
// Each WAVE owns one 16-row group end-to-end: x held in registers as MFMA
// B-fragments (lane = row lo, k-chunk hi -- exactly the HW B layout, so the
// per-lane global load IS the fragment load; no staging, no transpose).
// Sweep 16 o-tiles: transient W A-fragments from L2 (256KB working set,
// L2-hot), 44 MFMA/tile, U-fold + bias + tanh-GELU, 6 contiguous f32x4
// stores. No __syncthreads, no vmcnt-on-stores: waves drain stores in the
// background like the 7 TB/s fill kernel. x redundancy 1x (vs R2's 16x).
// Math identical to R18 (absmax 0.03125): out_n = GELU(c_n*U + x_n*M +
// x_partner*N + b), partners 2<->5, 3<->4; nodes 0,1 use M0, c=1/5.
__global__ __launch_bounds__(256, 2)
void sage_v17(const float* __restrict__ x, const short* __restrict__ Wb,
              const float* __restrict__ bias, float* __restrict__ out) {
    const int t = threadIdx.x;
    const int lane = t & 63;
    const int wv = t >> 6;
    const int lo = lane & 15;      // batch row within group / D col
    const int hi = lane >> 4;      // k-subchunk / D row-group
    const size_t g = (size_t)blockIdx.x * 4 + wv;   // group 0..2047
    const size_t row = g * 16 + lo;

    // ---- x fragments for all 6 nodes + T, straight from global (once)
    const float* xr = x + row * CD;
    short8 xf[6][4], tf[4];
    #pragma unroll
    for (int m = 0; m < 4; ++m) {
        const int off = m * 32 + hi * 8;
        f32x4 T0 = (f32x4){0.f,0.f,0.f,0.f}, T1 = (f32x4){0.f,0.f,0.f,0.f};
        #pragma unroll
        for (int s = 0; s < 6; ++s) {
            f32x4 a = *(const f32x4*)(xr + (size_t)s * (NB * CD) + off);
            f32x4 b = *(const f32x4*)(xr + (size_t)s * (NB * CD) + off + 4);
            T0 += a; T1 += b;
            xf[s][m] = pack8(a, b);
        }
        tf[m] = pack8(T0, T1);
    }

    float* orow = out + row * OUTW;

    #pragma unroll 1
    for (int ot = 0; ot < 16; ++ot) {
        const int ob = ot * 16;
        const f32x4 b4 = *(const f32x4*)&bias[ob + hi * 4];

        // transient W A-fragments (A layout: row = lane&15 = o-in-tile,
        // k = hi*8+e; R4-validated swapped-operand convention)
        short8 wp[4], wm0[4], wm2[4], wn[4];
        #pragma unroll
        for (int m = 0; m < 4; ++m) {
            const int idx = (ob + lo) * CD + m * 32 + hi * 8;
            wp[m]  = *(const short8*)&Wb[PW_P  + idx];
            wm0[m] = *(const short8*)&Wb[PW_M0 + idx];
            wm2[m] = *(const short8*)&Wb[PW_M2 + idx];
            wn[m]  = *(const short8*)&Wb[PW_N  + idx];
        }

        f32x4 aU = (f32x4){0.f,0.f,0.f,0.f};
        f32x4 ac[6];
        #pragma unroll
        for (int n = 0; n < 6; ++n) ac[n] = (f32x4){0.f,0.f,0.f,0.f};

        #pragma unroll
        for (int m = 0; m < 4; ++m) {
            aU    = __builtin_amdgcn_mfma_f32_16x16x32_bf16(wp[m],  tf[m],    aU,    0, 0, 0);
            ac[0] = __builtin_amdgcn_mfma_f32_16x16x32_bf16(wm0[m], xf[0][m], ac[0], 0, 0, 0);
            ac[1] = __builtin_amdgcn_mfma_f32_16x16x32_bf16(wm0[m], xf[1][m], ac[1], 0, 0, 0);
            ac[2] = __builtin_amdgcn_mfma_f32_16x16x32_bf16(wm2[m], xf[2][m], ac[2], 0, 0, 0);
            ac[2] = __builtin_amdgcn_mfma_f32_16x16x32_bf16(wn[m],  xf[5][m], ac[2], 0, 0, 0);
            ac[5] = __builtin_amdgcn_mfma_f32_16x16x32_bf16(wm2[m], xf[5][m], ac[5], 0, 0, 0);
            ac[5] = __builtin_amdgcn_mfma_f32_16x16x32_bf16(wn[m],  xf[2][m], ac[5], 0, 0, 0);
            ac[3] = __builtin_amdgcn_mfma_f32_16x16x32_bf16(wm2[m], xf[3][m], ac[3], 0, 0, 0);
            ac[3] = __builtin_amdgcn_mfma_f32_16x16x32_bf16(wn[m],  xf[4][m], ac[3], 0, 0, 0);
            ac[4] = __builtin_amdgcn_mfma_f32_16x16x32_bf16(wm2[m], xf[4][m], ac[4], 0, 0, 0);
            ac[4] = __builtin_amdgcn_mfma_f32_16x16x32_bf16(wn[m],  xf[3][m], ac[4], 0, 0, 0);
        }

        // epilogue: D col = lo (batch row), D rows = ob+hi*4+j -> lane's
        // f32x4 = 4 consecutive out floats (R4-validated). tanh-GELU.
        #pragma unroll
        for (int n = 0; n < 6; ++n) {
            const float cu = (n < 2) ? 0.2f : 0.25f;
            f32x4 v = ac[n] + b4;
            #pragma unroll
            for (int j = 0; j < 4; ++j) v[j] += cu * aU[j];
            f32x4 gl;
            #pragma unroll
            for (int j = 0; j < 4; ++j) {
                const float s = v[j] * (0.7978845608f + 0.0356774081f * v[j] * v[j]);
                const float rr = __builtin_amdgcn_exp2f(-2.885390082f * s);
                gl[j] = v[j] * __builtin_amdgcn_rcpf(1.0f + rr);
            }
            *(f32x4*)&orow[n * 256 + ob + hi * 4] = gl;
        }
    }
}

extern "C" void kernel_launch(void* const* d_in, const int* in_sizes, int n_in,
                              void* d_out, int out_size, void* d_ws, size_t ws_size,
                              hipStream_t stream) {
    const float* x  = (const float*)d_in[0];
    const float* Wl = (const float*)d_in[1];
    const float* Wr = (const float*)d_in[2];
    const float* b  = (const float*)d_in[3];
    float* out = (float*)d_out;
    short* Wb = (short*)d_ws;   // 4 x 64 KB bf16 weight combos = 256 KB

    prep_w<<<dim3(16), dim3(256), 0, stream>>>(Wl, Wr, Wb);
    // 2048 groups, 4 independent waves per 256-thread block
    sage_v17<<<dim3(512), dim3(256), 0, stream>>>(x, Wb, b, out);
}